// Round 10
// baseline (1007.094 us; speedup 1.0000x reference)
//
#include <hip/hip_runtime.h>
#include <hip/hip_bf16.h>

typedef unsigned short u16;
typedef unsigned int   u32;
typedef unsigned char  u8;

typedef __attribute__((ext_vector_type(8))) short bf16x8;
typedef __attribute__((ext_vector_type(4))) float f32x4;
typedef __attribute__((ext_vector_type(16))) float f32x16;

static __device__ __forceinline__ float bf2f(u16 u){ return __uint_as_float(((u32)u)<<16); }
static __device__ __forceinline__ u16 f2bf(float f){
  u32 u = __float_as_uint(f);
  u32 r = (u + 0x7fff + ((u>>16)&1)) >> 16;   // RNE; inputs finite
  return (u16)r;
}

// fp8 e4m3 (OCP) helpers — HW cvt, saturating via pre-clamp
static __device__ __forceinline__ u8 f2fp8(float v){
  v = fminf(440.f, fmaxf(-440.f, v));
  return (u8)(__builtin_amdgcn_cvt_pk_fp8_f32(v, 0.f, 0, false) & 0xff);
}
static __device__ __forceinline__ u32 pk4_fp8(float a, float b, float c, float d){
  int w = __builtin_amdgcn_cvt_pk_fp8_f32(a, b, 0, false);
  w = __builtin_amdgcn_cvt_pk_fp8_f32(c, d, w, true);
  return (u32)w;
}

static __device__ __forceinline__ f32x4 mfma_bf16(bf16x8 a, bf16x8 b, f32x4 c){
  return __builtin_amdgcn_mfma_f32_16x16x32_bf16(a, b, c, 0, 0, 0);
}
static __device__ __forceinline__ f32x16 mfma_bf16_32(bf16x8 a, bf16x8 b, f32x16 c){
  return __builtin_amdgcn_mfma_f32_32x32x16_bf16(a, b, c, 0, 0, 0);
}
static __device__ __forceinline__ f32x16 mfma_fp8_32(long a, long b, f32x16 c){
  return __builtin_amdgcn_mfma_f32_32x32x16_fp8_fp8(a, b, c, 0, 0, 0);
}
static __device__ __forceinline__ long lo64(uint4 v){ return (long)(((unsigned long long)v.y<<32) | v.x); }
static __device__ __forceinline__ long hi64(uint4 v){ return (long)(((unsigned long long)v.w<<32) | v.z); }
static __device__ __forceinline__ long mklong(u32 lo, u32 hi){ return (long)(((unsigned long long)hi<<32) | lo); }

// ---------------------------------------------------------------------------
// K-w8: W f32 [m][k] -> fp8 packed, 1KB block per (pt=m/64, kt=k/32, mcp):
//   byte at lane*16 + sel*8 + j = W[pt*64 + (mcp*2+sel)*16 + (lane>>5)*8 + j][kt*32 + (lane&31)]
// grid (32,32,2), block 256.
// ---------------------------------------------------------------------------
__global__ void k_w8(const float* __restrict__ Wc, const float* __restrict__ Wd,
                     u8* __restrict__ Wc8, u8* __restrict__ Wd8){
  __shared__ float tile[64][65];
  const float* src = blockIdx.z ? Wd : Wc;
  u8* dst = blockIdx.z ? Wd8 : Wc8;
  const int m0 = blockIdx.x*64, k0 = blockIdx.y*64;
  const int t = threadIdx.x, r = t & 63, cc = t >> 6;
  #pragma unroll
  for (int j=0;j<4;j++){
    float4 v = *(const float4*)&src[(size_t)(m0+r)*2048 + k0 + cc*16 + j*4];
    tile[r][cc*16+j*4+0]=v.x; tile[r][cc*16+j*4+1]=v.y;
    tile[r][cc*16+j*4+2]=v.z; tile[r][cc*16+j*4+3]=v.w;
  }
  __syncthreads();
  const int lane = t & 63, sub = t >> 6;     // sub 0..3
  const int kth = sub & 1, mcp = sub >> 1;
  const int kl = kth*32 + (lane & 31);       // k within 64-tile
  const int ml = mcp*32 + (lane >> 5)*8;     // m base within 64-tile
  u32 b0 = pk4_fp8(16.f*tile[ml+ 0][kl], 16.f*tile[ml+ 1][kl], 16.f*tile[ml+ 2][kl], 16.f*tile[ml+ 3][kl]);
  u32 b1 = pk4_fp8(16.f*tile[ml+ 4][kl], 16.f*tile[ml+ 5][kl], 16.f*tile[ml+ 6][kl], 16.f*tile[ml+ 7][kl]);
  u32 b2 = pk4_fp8(16.f*tile[ml+16][kl], 16.f*tile[ml+17][kl], 16.f*tile[ml+18][kl], 16.f*tile[ml+19][kl]);
  u32 b3 = pk4_fp8(16.f*tile[ml+20][kl], 16.f*tile[ml+21][kl], 16.f*tile[ml+22][kl], 16.f*tile[ml+23][kl]);
  const int pt = m0 >> 6, kt = (k0 >> 5) + kth;
  u8* dbase = dst + (size_t)((pt*64 + kt)*2 + mcp)*1024 + lane*16;
  *(uint4*)dbase = make_uint4(b0, b1, b2, b3);
}

// ---------------------------------------------------------------------------
// K-hcvt: h f32 [b][m][64] -> hb16 (bf16 row-major), hfm (bf16 frag-major B for
// phase 1), ht8p (fp8 32x32x16-B frags). grid (32,16), block 256.
// ---------------------------------------------------------------------------
__global__ void k_hcvt(const float* __restrict__ h, u16* __restrict__ hb16,
                       u8* __restrict__ ht8p, u16* __restrict__ hfm){
  __shared__ float tile[64][65];
  const int k0 = blockIdx.x*64, b = blockIdx.y;
  const int t = threadIdx.x, r = t & 63, cc = t >> 6;
  const float* src = h + ((size_t)b*2048 + k0)*64;
  u32 hw[8];
  #pragma unroll
  for (int j=0;j<4;j++){
    float4 v = *(const float4*)&src[(size_t)r*64 + cc*16 + j*4];
    tile[r][cc*16+j*4+0]=v.x; tile[r][cc*16+j*4+1]=v.y;
    tile[r][cc*16+j*4+2]=v.z; tile[r][cc*16+j*4+3]=v.w;
    hw[2*j]   = (u32)f2bf(v.x) | ((u32)f2bf(v.y)<<16);
    hw[2*j+1] = (u32)f2bf(v.z) | ((u32)f2bf(v.w)<<16);
  }
  u16* hp = hb16 + (((size_t)b*2048 + k0 + r)*64 + cc*16);
  *(uint4*)hp     = make_uint4(hw[0],hw[1],hw[2],hw[3]);
  *(uint4*)(hp+8) = make_uint4(hw[4],hw[5],hw[6],hw[7]);
  __syncthreads();
  {
    const int lane = t & 63, sub = cc;          // sub = local k16 index 0..3
    const int k16 = (k0 >> 4) + sub;
    const int lr = sub*16 + ((lane >> 5) << 3); // local row in tile
    const int d0 = lane & 31;
    #pragma unroll
    for (int dt=0; dt<2; ++dt){
      const int d = dt*32 + d0;
      u32 w0 = pk4_fp8(tile[lr+0][d], tile[lr+1][d], tile[lr+2][d], tile[lr+3][d]);
      u32 w1 = pk4_fp8(tile[lr+4][d], tile[lr+5][d], tile[lr+6][d], tile[lr+7][d]);
      *(uint2*)(ht8p + (size_t)b*131072 + (size_t)(k16*2 + dt)*512 + lane*8) = make_uint2(w0, w1);
    }
  }
  {
    const int col = k0 + r, ks = cc >> 1, q0 = (cc & 1)*2;
    const int ctg = col >> 4, lcv = col & 15;
    u16* fbase = hfm + (size_t)b*131072 + (size_t)ks*65536 + ((size_t)ctg*64)*8;
    #pragma unroll
    for (int qq=0; qq<2; ++qq){
      int q = q0 + qq;
      u32 p0 = (u32)f2bf(tile[r][ks*32+q*8+0]) | ((u32)f2bf(tile[r][ks*32+q*8+1])<<16);
      u32 p1 = (u32)f2bf(tile[r][ks*32+q*8+2]) | ((u32)f2bf(tile[r][ks*32+q*8+3])<<16);
      u32 p2 = (u32)f2bf(tile[r][ks*32+q*8+4]) | ((u32)f2bf(tile[r][ks*32+q*8+5])<<16);
      u32 p3 = (u32)f2bf(tile[r][ks*32+q*8+6]) | ((u32)f2bf(tile[r][ks*32+q*8+7])<<16);
      *(uint4*)(fbase + (size_t)(q*16 + lcv)*8) = make_uint4(p0,p1,p2,p3);
    }
  }
}

// ---------------------------------------------------------------------------
// K1: row n of A = E E^T. sign-mask (1 pos, 2 neg) + P=softmax(relu) bf16.
// ---------------------------------------------------------------------------
__global__ void k_P(const float* __restrict__ E, u16* __restrict__ P, u8* __restrict__ msk){
  __shared__ float Ew[16];
  __shared__ float arow[2048];
  __shared__ float red[4];
  const int t = threadIdx.x, n = blockIdx.x;
  if (t < 16) Ew[t] = E[n*16 + t];
  __syncthreads();
  float lmax = 0.f;
  for (int i=0;i<8;i++){
    int m = t + 256*i;
    const float4* ep = (const float4*)(E + m*16);
    float4 e0 = ep[0], e1 = ep[1], e2 = ep[2], e3 = ep[3];
    float dot = e0.x*Ew[0] + e0.y*Ew[1] + e0.z*Ew[2] + e0.w*Ew[3]
              + e1.x*Ew[4] + e1.y*Ew[5] + e1.z*Ew[6] + e1.w*Ew[7]
              + e2.x*Ew[8] + e2.y*Ew[9] + e2.z*Ew[10] + e2.w*Ew[11]
              + e3.x*Ew[12] + e3.y*Ew[13] + e3.z*Ew[14] + e3.w*Ew[15];
    msk[n*2048 + m] = dot > 0.f ? (u8)1 : (dot < 0.f ? (u8)2 : (u8)0);
    float ar = fmaxf(dot, 0.f);
    arow[m] = ar;
    lmax = fmaxf(lmax, ar);
  }
  for (int o=1;o<64;o<<=1) lmax = fmaxf(lmax, __shfl_xor(lmax, o));
  if ((t&63)==0) red[t>>6] = lmax;
  __syncthreads();
  float gmax = fmaxf(fmaxf(red[0],red[1]), fmaxf(red[2],red[3]));
  __syncthreads();
  float lsum = 0.f;
  for (int i=0;i<8;i++){
    int m = t + 256*i;
    float e = expf(arow[m] - gmax);
    arow[m] = e;
    lsum += e;
  }
  for (int o=1;o<64;o<<=1) lsum += __shfl_xor(lsum, o);
  if ((t&63)==0) red[t>>6] = lsum;
  __syncthreads();
  float inv = 1.f/(red[0]+red[1]+red[2]+red[3]);
  for (int i=0;i<8;i++){
    int m = t + 256*i;
    P[n*2048 + m] = f2bf(arow[m]*inv);
  }
}

// ---------------------------------------------------------------------------
// K-mbits: LDS-tiled transpose bitmap build. grid (32, 8), block 256.
// ---------------------------------------------------------------------------
__global__ void k_mbits(const u8* __restrict__ msk, u32* __restrict__ mp2, u32* __restrict__ mn2){
  __shared__ u8 tile[256][72];
  const int m0 = blockIdx.x*64, n0 = blockIdx.y*256;
  const int t = threadIdx.x;
  {
    const u8* src = msk + (size_t)(n0 + t)*2048 + m0;
    #pragma unroll
    for (int j=0;j<8;j++)
      *(uint2*)&tile[t][j*8] = *(const uint2*)(src + j*8);
  }
  __syncthreads();
  const int m = t & 63, g = t >> 6;
  #pragma unroll
  for (int jj=0; jj<2; ++jj){
    const int j = g + jj*4;                 // n-word 0..7 within tile
    u32 bp = 0, bn = 0;
    #pragma unroll
    for (int i=0;i<32;++i){
      u8 v = tile[j*32 + i][m];
      bp |= (u32)(v == (u8)1) << i;
      bn |= (u32)(v == (u8)2) << i;
    }
    const size_t wi = (size_t)((n0 >> 5) + j)*2048 + m0 + m;
    mp2[wi] = bp;
    mn2[wi] = bn;
  }
}

// ---------------------------------------------------------------------------
// K2: Y[b,n,d] = sum_m P[n,m] * Z[b,m,d] via bf16 MFMA with hi/lo split.
// withx=1 additionally computes c1x from the staged P tile.
// grid (32,16), block 256.
// ---------------------------------------------------------------------------
__global__ void k_conv(const u16* __restrict__ P, const float* __restrict__ Z, float* __restrict__ Y,
                       const float* __restrict__ x, float* __restrict__ c1x, int withx){
  __shared__ u16 Pt[64][68];
  __shared__ u16 Zhi[64][68];
  __shared__ u16 Zlo[64][68];
  __shared__ float xt[64][2];
  const int t = threadIdx.x;
  const int w = t >> 6, lane = t & 63, l32 = lane & 31, h32 = lane >> 5;
  const int nh = w & 1, dh = w >> 1;
  const int n0 = blockIdx.x*64, b = blockIdx.y;
  const int mloc = t & 63, grp = t >> 6;
  f32x16 acch = (f32x16)(0.f), accl = (f32x16)(0.f);
  float xacc = 0.f;
  const int xnl = t >> 2, xc = (t >> 1) & 1, xmh = t & 1;
  for (int mc = 0; mc < 32; ++mc){
    const int m0 = mc*64;
    {
      const u16* pp = P + (size_t)(n0 + mloc)*2048 + m0 + grp*16;
      uint4 v0 = *(const uint4*)pp;
      uint4 v1 = *(const uint4*)(pp + 8);
      *(uint4*)&Pt[mloc][grp*16]     = v0;
      *(uint4*)&Pt[mloc][grp*16 + 8] = v1;
      const float* zp = Z + ((size_t)b*2048 + m0 + mloc)*64 + grp*16;
      #pragma unroll
      for (int jj = 0; jj < 4; ++jj){
        float4 zv = *(const float4*)(zp + jj*4);
        const int dd = grp*16 + jj*4;
        u16 h0 = f2bf(zv.x); Zhi[dd+0][mloc] = h0; Zlo[dd+0][mloc] = f2bf(zv.x - bf2f(h0));
        u16 h1 = f2bf(zv.y); Zhi[dd+1][mloc] = h1; Zlo[dd+1][mloc] = f2bf(zv.y - bf2f(h1));
        u16 h2 = f2bf(zv.z); Zhi[dd+2][mloc] = h2; Zlo[dd+2][mloc] = f2bf(zv.z - bf2f(h2));
        u16 h3 = f2bf(zv.w); Zhi[dd+3][mloc] = h3; Zlo[dd+3][mloc] = f2bf(zv.w - bf2f(h3));
      }
      if (withx && t < 128)
        xt[t>>1][t&1] = x[((size_t)b*2048 + m0 + (t>>1))*2 + (t&1)];
    }
    __syncthreads();
    #pragma unroll
    for (int kt = 0; kt < 4; ++kt){
      bf16x8 a  = *(const bf16x8*)&Pt[nh*32 + l32][kt*16 + h32*8];
      bf16x8 bh = *(const bf16x8*)&Zhi[dh*32 + l32][kt*16 + h32*8];
      bf16x8 bl = *(const bf16x8*)&Zlo[dh*32 + l32][kt*16 + h32*8];
      acch = mfma_bf16_32(a, bh, acch);
      accl = mfma_bf16_32(a, bl, accl);
    }
    if (withx){
      #pragma unroll
      for (int mi = 0; mi < 32; ++mi){
        const int ml = xmh*32 + mi;
        xacc += bf2f(Pt[xnl][ml])*xt[ml][xc];
      }
    }
    __syncthreads();
  }
  #pragma unroll
  for (int g = 0; g < 16; ++g){
    const int row = (g&3) + 8*(g>>2) + 4*h32;
    Y[((size_t)b*2048 + n0 + nh*32 + row)*64 + dh*32 + l32] = acch[g] + accl[g];
  }
  if (withx){
    float o = xacc + __shfl_xor(xacc, 1);
    if (xmh == 0)
      c1x[((size_t)b*2048 + n0 + xnl)*2 + xc] = o;
  }
}

// ---------------------------------------------------------------------------
// K3 (R17): gate SAGC, TWO nodes per block (512 thr). Each gw value is loaded
// once and MAC'd into both nodes' Wn -> gw L2 stream halves. Big arrays in
// DYNAMIC LDS (R16's static 73 KB exceeded the 64 KB static limit — likely
// the container failure): Wn 2x2x66x64 f32 = 67.6 KB + xg4 4.2 KB = 71.8 KB
// dynamic, opted in via hipFuncSetAttribute. grid 1024, block 512.
// ---------------------------------------------------------------------------
#define GATE_LDS (2*2*66*64*4 + 2*4*2*66*4)

__global__ void k_gate(const float* __restrict__ E, const float* __restrict__ gw, const float* __restrict__ gb,
                       const float* __restrict__ x, const float* __restrict__ state,
                       const float* __restrict__ c1x, const float* __restrict__ c1s,
                       float* __restrict__ zs, float* __restrict__ rws){
  extern __shared__ float dyn[];
  float* Wn  = dyn;                        // [nd][k][i][o] = ((nd*2+k)*66+i)*64+o
  float* xg4 = dyn + 2*2*66*64;            // [nd][bi][k][i] = ((nd*4+bi)*2+k)*66+i
  __shared__ float Ew[2][16];
  __shared__ float bnv[2][128];
  const int t = threadIdx.x, n0 = blockIdx.x*2;
  if (t < 32) Ew[t>>4][t&15] = E[(n0 + (t>>4))*16 + (t&15)];
  __syncthreads();
  if (t < 256){
    const int nd = t >> 7, o = t & 127;
    float a = 0.f;
    #pragma unroll
    for (int e=0;e<16;e++) a += Ew[nd][e]*gb[e*128 + o];
    bnv[nd][o] = a;
  }
  for (int half=0; half<2; ++half){
    for (int idx=t; idx<8448; idx+=512){
      int o = idx & 63, rest = idx>>6, i = rest % 66, k = rest / 66;
      float a0 = 0.f, a1 = 0.f;
      #pragma unroll
      for (int e=0;e<16;e++){
        float g = gw[((e*2+k)*66 + i)*128 + half*64 + o];
        a0 += Ew[0][e]*g;
        a1 += Ew[1][e]*g;
      }
      Wn[((0*2+k)*66 + i)*64 + o] = a0;
      Wn[((1*2+k)*66 + i)*64 + o] = a1;
    }
    __syncthreads();
    for (int bb=0; bb<4; ++bb){
      for (int idx=t; idx<1056; idx+=512){
        int nd = idx/528, rem = idx%528, bi = rem/132, r2 = rem%132, k = r2/66, i = r2%66;
        int b = bb*4 + bi, n = n0 + nd;
        float v;
        if (k==0) v = (i<2) ? x[((size_t)b*2048+n)*2 + i] : state[((size_t)b*2048+n)*64 + (i-2)];
        else      v = (i<2) ? c1x[((size_t)b*2048+n)*2 + i] : c1s[((size_t)b*2048+n)*64 + (i-2)];
        xg4[((nd*4+bi)*2 + k)*66 + i] = v;
      }
      __syncthreads();
      {
        int wv = t>>6, nd = wv>>2, bi = wv&3, o = t&63;
        int b = bb*4 + bi, n = n0 + nd;
        float a = 0.f;
        #pragma unroll
        for (int k=0;k<2;k++)
          for (int i=0;i<66;i++)
            a += xg4[((nd*4+bi)*2 + k)*66 + i]*Wn[((nd*2+k)*66 + i)*64 + o];
        a += bnv[nd][half*64 + o];
        float s = 1.f/(1.f + expf(-a));
        if (half==0) zs[((size_t)b*2048+n)*64 + o] = s*state[((size_t)b*2048+n)*64 + o];
        else         rws[((size_t)b*2048+n)*64 + o] = s;
      }
      __syncthreads();
    }
  }
}

// ---------------------------------------------------------------------------
// K3b (R17): update SAGC, TWO nodes per block (512 thr), dynamic LDS.
// grid 1024, block 512.
// ---------------------------------------------------------------------------
__global__ void k_upd(const float* __restrict__ E, const float* __restrict__ uw, const float* __restrict__ ub,
                      const float* __restrict__ x, const float* __restrict__ state,
                      const float* __restrict__ zs, const float* __restrict__ c1x, const float* __restrict__ c2s,
                      const float* __restrict__ rws, float* __restrict__ h){
  extern __shared__ float dyn[];
  float* Wn  = dyn;                        // [nd][k][i][o]
  float* xg4 = dyn + 2*2*66*64;            // [nd][bi][k][i]
  __shared__ float Ew[2][16];
  __shared__ float bnu[2][64];
  const int t = threadIdx.x, n0 = blockIdx.x*2;
  if (t < 32) Ew[t>>4][t&15] = E[(n0 + (t>>4))*16 + (t&15)];
  __syncthreads();
  if (t < 128){
    const int nd = t >> 6, o = t & 63;
    float a = 0.f;
    #pragma unroll
    for (int e=0;e<16;e++) a += Ew[nd][e]*ub[e*64 + o];
    bnu[nd][o] = a;
  }
  for (int idx=t; idx<8448; idx+=512){
    int o = idx & 63, rest = idx>>6, i = rest % 66, k = rest / 66;
    float a0 = 0.f, a1 = 0.f;
    #pragma unroll
    for (int e=0;e<16;e++){
      float g = uw[((e*2+k)*66 + i)*64 + o];
      a0 += Ew[0][e]*g;
      a1 += Ew[1][e]*g;
    }
    Wn[((0*2+k)*66 + i)*64 + o] = a0;
    Wn[((1*2+k)*66 + i)*64 + o] = a1;
  }
  __syncthreads();
  for (int bb=0; bb<4; ++bb){
    for (int idx=t; idx<1056; idx+=512){
      int nd = idx/528, rem = idx%528, bi = rem/132, r2 = rem%132, k = r2/66, i = r2%66;
      int b = bb*4 + bi, n = n0 + nd;
      float v;
      if (k==0) v = (i<2) ? x[((size_t)b*2048+n)*2 + i] : zs[((size_t)b*2048+n)*64 + (i-2)];
      else      v = (i<2) ? c1x[((size_t)b*2048+n)*2 + i] : c2s[((size_t)b*2048+n)*64 + (i-2)];
      xg4[((nd*4+bi)*2 + k)*66 + i] = v;
    }
    __syncthreads();
    {
      int wv = t>>6, nd = wv>>2, bi = wv&3, o = t&63;
      int b = bb*4 + bi, n = n0 + nd;
      float a = 0.f;
      #pragma unroll
      for (int k=0;k<2;k++)
        for (int i=0;i<66;i++)
          a += xg4[((nd*4+bi)*2 + k)*66 + i]*Wn[((nd*2+k)*66 + i)*64 + o];
      float hc = tanhf(a + bnu[nd][o]);
      float rv = rws[((size_t)b*2048+n)*64 + o];
      h[((size_t)b*2048+n)*64 + o] = rv*state[((size_t)b*2048+n)*64 + o] + (1.f - rv)*hc;
    }
    __syncthreads();
  }
}

// ---------------------------------------------------------------------------
// sm_step2: both n-halves' online-softmax steps fused; ht frags loaded once.
// ---------------------------------------------------------------------------
static __device__ __forceinline__ void sm_step2(
    f32x16& L00, f32x16& L10, f32x16& L01, f32x16& L11,
    f32x16& oA0, f32x16& oA1, f32x16& oB0, f32x16& oB1,
    float& mrun0, float& srun0, float& mrun1, float& srun1,
    const u8* __restrict__ htb, int ktA, int ktB, int lane, int h32){
  const float LN256 = 5.545177444479562f;
  float c0 = L00[0], c1 = L01[0];
  #pragma unroll
  for (int g=1; g<16; ++g){ c0 = fmaxf(c0, L00[g]); c1 = fmaxf(c1, L01[g]); }
  #pragma unroll
  for (int g=0; g<16; ++g){ c0 = fmaxf(c0, L10[g]); c1 = fmaxf(c1, L11[g]); }
  c0 = fmaxf(c0, __shfl_xor(c0, 32));
  c1 = fmaxf(c1, __shfl_xor(c1, 32));
  float mnew0 = fmaxf(mrun0, 0.5f*c0);
  float mnew1 = fmaxf(mrun1, 0.5f*c1);
  float sc0 = __expf(mrun0 - mnew0);
  float sc1 = __expf(mrun1 - mnew1);
  srun0 *= sc0; srun1 *= sc1;
  #pragma unroll
  for (int g=0; g<16; ++g){
    const int rowl = (g&3) + 8*(g>>2) + 4*h32;
    float f0 = __shfl(sc0, rowl);
    float f1 = __shfl(sc1, rowl);
    oA0[g] *= f0; oA1[g] *= f0;
    oB0[g] *= f1; oB1[g] *= f1;
  }
  float cs0 = 0.f, cs1 = 0.f;
  #pragma unroll
  for (int kti=0; kti<2; ++kti){
    const int kt = kti ? ktB : ktA;
    long h00 = *(const long*)(htb + (size_t)((kt*2+0)*2 + 0)*512 + lane*8);
    long h01 = *(const long*)(htb + (size_t)((kt*2+0)*2 + 1)*512 + lane*8);
    long h10 = *(const long*)(htb + (size_t)((kt*2+1)*2 + 0)*512 + lane*8);
    long h11 = *(const long*)(htb + (size_t)((kt*2+1)*2 + 1)*512 + lane*8);
    float p0[16], p1[16];
    #pragma unroll
    for (int g=0; g<16; ++g){
      float La = kti ? L10[g] : L00[g];
      float Lb = kti ? L11[g] : L01[g];
      p0[g] = __expf(0.5f*La - mnew0 + LN256);   // 256-scaled
      p1[g] = __expf(0.5f*Lb - mnew1 + LN256);
      cs0 += p0[g]; cs1 += p1[g];
    }
    u32 qA0 = pk4_fp8(p0[0],p0[1],p0[2],p0[3]);
    u32 qB0 = pk4_fp8(p0[4],p0[5],p0[6],p0[7]);
    u32 qC0 = pk4_fp8(p0[8],p0[9],p0[10],p0[11]);
    u32 qD0 = pk4_fp8(p0[12],p0[13],p0[14],p0[15]);
    u32 qA1 = pk4_fp8(p1[0],p1[1],p1[2],p1[3]);
    u32 qB1 = pk4_fp8(p1[4],p1[5],p1[6],p1[7]);
    u32 qC1 = pk4_fp8(p1[8],p1[9],p1[10],p1[11]);
    u32 qD1 = pk4_fp8(p1[12],p1[13],p1[14],p1[15]);
    u32 xA0 = __shfl_xor(qA0,32), xB0 = __shfl_xor(qB0,32);
    u32 xC0 = __shfl_xor(qC0,32), xD0 = __shfl_xor(qD0,32);
    u32 xA1 = __shfl_xor(qA1,32), xB1 = __shfl_xor(qB1,32);
    u32 xC1 = __shfl_xor(qC1,32), xD1 = __shfl_xor(qD1,32);
    long pf00 = h32 ? mklong(xB0,qB0) : mklong(qA0,xA0);
    long pf01 = h32 ? mklong(xD0,qD0) : mklong(qC0,xC0);
    long pf10 = h32 ? mklong(xB1,qB1) : mklong(qA1,xA1);
    long pf11 = h32 ? mklong(xD1,qD1) : mklong(qC1,xC1);
    oA0 = mfma_fp8_32(pf00, h00, oA0);
    oA1 = mfma_fp8_32(pf00, h01, oA1);
    oB0 = mfma_fp8_32(pf10, h00, oB0);
    oB1 = mfma_fp8_32(pf10, h01, oB1);
    oA0 = mfma_fp8_32(pf01, h10, oA0);
    oA1 = mfma_fp8_32(pf01, h11, oA1);
    oB0 = mfma_fp8_32(pf11, h10, oB0);
    oB1 = mfma_fp8_32(pf11, h11, oB1);
  }
  cs0 += __shfl_xor(cs0, 32);
  cs1 += __shfl_xor(cs1, 32);
  srun0 += cs0; srun1 += cs1;
  mrun0 = mnew0; mrun1 = mnew1;
}

// ---------------------------------------------------------------------------
// K5: fused degrees — R17 (= R16 retry): + anti-phase si stagger. With 2
// waves/SIMD and no barriers in the si loop, waves self-lockstep via pipe
// contention. Rotating one SIMD-pair wave's si order by 2 puts the pair in
// anti-phase: MFMA burst of one overlaps sm_step VALU of the other (setprio
// maintains it). Online softmax is chunk-order independent -> math unchanged.
// ---------------------------------------------------------------------------
#define SROW8 2056

__global__ void __launch_bounds__(512,2) k_deg(
    const u32* __restrict__ mbits, const u16* __restrict__ hb16,
    const u8* __restrict__ W8,
    const u8* __restrict__ ht8p, const u16* __restrict__ hfm,
    const float* __restrict__ hf32, const float* __restrict__ oc_in,
    float* __restrict__ outp, int fin){
  extern __shared__ u8 S[];
  __shared__ float maxw[64][8];
  __shared__ float sumw[64][8];
  __shared__ float sgl_lds[64];
  const int t = threadIdx.x;
  const int w = t >> 6, lane = t & 63, lc = lane & 15, q = lane >> 4;
  const int l32 = lane & 31, h32 = lane >> 5;
  const int id = blockIdx.x;
  const int b = id >> 5, n0 = (id & 31) * 64;
  const int p0 = (id >> 3) & 31;          // per-CU-within-XCD rotation offset
  const u32* mrow0 = mbits + (size_t)(n0 >> 5)*2048;
  const u32* mrow1 = mrow0 + 2048;
  const u16* hbb = hb16 + (size_t)b*2048*64;
  const u16* hfb = hfm + (size_t)b*131072;
  const u8* htb = ht8p + (size_t)b*131072;

  // ---- phase 1: S[r][m] = fp8( (bit ? h_n.h_m : 0) / 8 ), 64 rows ----
  {
    const int c0 = p0 & 15;
    bf16x8 A[4][2];
    #pragma unroll
    for (int rt=0; rt<4; ++rt)
      #pragma unroll
      for (int ks=0; ks<2; ++ks)
        A[rt][ks] = *(const bf16x8*)&hbb[(size_t)(n0 + rt*16 + lc)*64 + ks*32 + q*8];
    int ctg0 = w*16 + c0;
    bf16x8 B0c = *(const bf16x8*)(hfb + (size_t)ctg0*512 + lane*8);
    bf16x8 B1c = *(const bf16x8*)(hfb + 65536 + (size_t)ctg0*512 + lane*8);
    u32 m0c = mrow0[ctg0*16 + lc], m1c = mrow1[ctg0*16 + lc];
    #pragma unroll 1
    for (int ct=0; ct<16; ++ct){
      const int ctg  = w*16 + ((ct + c0) & 15);
      const int ctgn = w*16 + ((ct + 1 + c0) & 15);
      bf16x8 B0n = *(const bf16x8*)(hfb + (size_t)ctgn*512 + lane*8);
      bf16x8 B1n = *(const bf16x8*)(hfb + 65536 + (size_t)ctgn*512 + lane*8);
      u32 m0n = mrow0[ctgn*16 + lc], m1n = mrow1[ctgn*16 + lc];
      const int mcol = ctg*16 + lc;
      f32x4 a[4];
      #pragma unroll
      for (int rt=0; rt<4; ++rt){
        a[rt] = (f32x4){0.f,0.f,0.f,0.f};
        a[rt] = mfma_bf16(A[rt][0], B0c, a[rt]);
        a[rt] = mfma_bf16(A[rt][1], B1c, a[rt]);
      }
      #pragma unroll
      for (int rt=0; rt<4; ++rt){
        const u32 mw = (rt < 2) ? m0c : m1c;
        #pragma unroll
        for (int i=0;i<4;i++){
          const int row = rt*16 + q*4 + i;
          float v = ((mw >> (row & 31)) & 1u) ? a[rt][i]*0.125f : 0.f;
          S[row*SROW8 + mcol] = f2fp8(v);
        }
      }
      B0c = B0n; B1c = B1n; m0c = m0n; m1c = m1n;
    }
  }
  __syncthreads();

  // ---- fused phases 2+3+4: wave w owns k-cols [w*256,(w+1)*256), all 64 n ----
  const u8* sb0 = S + (size_t)l32*SROW8 + h32*8;          // nh0 rows
  const u8* sb1 = S + (size_t)(32 + l32)*SROW8 + h32*8;   // nh1 rows
  const u8* wl = W8 + lane*16;
  f32x16 oA0 = (f32x16)(0.f), oA1 = (f32x16)(0.f);        // nh0: dt0, dt1
  f32x16 oB0 = (f32x16)(0.f), oB1 = (f32x16)(0.f);        // nh1
  float mrun0 = -1e30f, srun0 = 0.f, mrun1 = -1e30f, srun1 = 0.f;
  const int sroff = ((w >> 2) & 1) * 2;   // anti-phase stagger for SIMD pair
  #pragma unroll 1
  for (int sii = 0; sii < 4; ++sii){
    const int si = (sii + sroff) & 3;
    const int ktA = w*8 + si*2, ktB = ktA + 1;
    f32x16 L00 = (f32x16)(0.f), L01 = (f32x16)(0.f);      // kti0: nh0, nh1
    f32x16 L10 = (f32x16)(0.f), L11 = (f32x16)(0.f);      // kti1
    uint4 wv0, wv1, wv2, wv3;
    {
      const int pt0 = p0;
      wv0 = *(const uint4*)(wl + (size_t)((pt0*64 + ktA)*2 + 0)*1024);
      wv1 = *(const uint4*)(wl + (size_t)((pt0*64 + ktA)*2 + 1)*1024);
      wv2 = *(const uint4*)(wl + (size_t)((pt0*64 + ktB)*2 + 0)*1024);
      wv3 = *(const uint4*)(wl + (size_t)((pt0*64 + ktB)*2 + 1)*1024);
    }
    __builtin_amdgcn_s_setprio(1);
    #pragma unroll 1
    for (int pti = 0; pti < 32; ++pti){
      const int pt  = (pti + p0) & 31;
      const int ptn = (pti + 1 + p0) & 31;
      long b00 = *(const long*)(sb0 + pt*64 +  0);
      long b01 = *(const long*)(sb0 + pt*64 + 16);
      long b02 = *(const long*)(sb0 + pt*64 + 32);
      long b03 = *(const long*)(sb0 + pt*64 + 48);
      long b10 = *(const long*)(sb1 + pt*64 +  0);
      long b11 = *(const long*)(sb1 + pt*64 + 16);
      long b12 = *(const long*)(sb1 + pt*64 + 32);
      long b13 = *(const long*)(sb1 + pt*64 + 48);
      uint4 wn0 = *(const uint4*)(wl + (size_t)((ptn*64 + ktA)*2 + 0)*1024);
      uint4 wn1 = *(const uint4*)(wl + (size_t)((ptn*64 + ktA)*2 + 1)*1024);
      uint4 wn2 = *(const uint4*)(wl + (size_t)((ptn*64 + ktB)*2 + 0)*1024);
      uint4 wn3 = *(const uint4*)(wl + (size_t)((ptn*64 + ktB)*2 + 1)*1024);
      L00 = mfma_fp8_32(lo64(wv0), b00, L00);
      L01 = mfma_fp8_32(lo64(wv0), b10, L01);
      L10 = mfma_fp8_32(lo64(wv2), b00, L10);
      L11 = mfma_fp8_32(lo64(wv2), b10, L11);
      L00 = mfma_fp8_32(hi64(wv0), b01, L00);
      L01 = mfma_fp8_32(hi64(wv0), b11, L01);
      L10 = mfma_fp8_32(hi64(wv2), b01, L10);
      L11 = mfma_fp8_32(hi64(wv2), b11, L11);
      L00 = mfma_fp8_32(lo64(wv1), b02, L00);
      L01 = mfma_fp8_32(lo64(wv1), b12, L01);
      L10 = mfma_fp8_32(lo64(wv3), b02, L10);
      L11 = mfma_fp8_32(lo64(wv3), b12, L11);
      L00 = mfma_fp8_32(hi64(wv1), b03, L00);
      L01 = mfma_fp8_32(hi64(wv1), b13, L01);
      L10 = mfma_fp8_32(hi64(wv3), b03, L10);
      L11 = mfma_fp8_32(hi64(wv3), b13, L11);
      wv0 = wn0; wv1 = wn1; wv2 = wn2; wv3 = wn3;
    }
    __builtin_amdgcn_s_setprio(0);
    sm_step2(L00, L10, L01, L11, oA0, oA1, oB0, oB1,
             mrun0, srun0, mrun1, srun1, htb, ktA, ktB, lane, h32);
  }

  // ---- merge: log-sum-exp combine of 8 k-slices ----
  if (h32 == 0){
    maxw[l32][w] = mrun0;      sumw[l32][w] = srun0;
    maxw[32 + l32][w] = mrun1; sumw[32 + l32][w] = srun1;
  }
  __syncthreads();                        // all S reads done; max/sum visible
  float* scr = (float*)S;
  {
    float m_g0 = maxw[l32][0];
    #pragma unroll
    for (int j=1;j<8;j++) m_g0 = fmaxf(m_g0, maxw[l32][j]);
    float s_g0 = 0.f;
    #pragma unroll
    for (int j=0;j<8;j++) s_g0 += sumw[l32][j]*__expf(maxw[l32][j]-m_g0);
    float m_g1 = maxw[32+l32][0];
    #pragma unroll
    for (int j=1;j<8;j++) m_g1 = fmaxf(m_g1, maxw[32+l32][j]);
    float s_g1 = 0.f;
    #pragma unroll
    for (int j=0;j<8;j++) s_g1 += sumw[32+l32][j]*__expf(maxw[32+l32][j]-m_g1);
    if (w == 0 && h32 == 0){
      sgl_lds[l32] = s_g0;
      sgl_lds[32 + l32] = s_g1;
    }
    float f0 = __expf(mrun0 - m_g0);
    float f1 = __expf(mrun1 - m_g1);
    #pragma unroll
    for (int g=0; g<16; ++g){
      const int rowl = (g&3) + 8*(g>>2) + 4*h32;
      float fr0 = __shfl(f0, rowl);
      float fr1 = __shfl(f1, rowl);
      scr[((size_t)w*64 + rowl)*64 + l32]           = oA0[g]*fr0;
      scr[((size_t)w*64 + rowl)*64 + 32 + l32]      = oA1[g]*fr0;
      scr[((size_t)w*64 + 32 + rowl)*64 + l32]      = oB0[g]*fr1;
      scr[((size_t)w*64 + 32 + rowl)*64 + 32 + l32] = oB1[g]*fr1;
    }
  }
  __syncthreads();

  // ---- reduce 8 partials + epilogue ----
  {
    const int n_g = t >> 3, d0 = (t & 7)*8;
    const float sdiv = sgl_lds[n_g];
    float* op = outp + (size_t)b*2048*64;
    const float* hp = hf32 + (size_t)b*2048*64;
    const float* cp = oc_in + (size_t)b*2048*64;
    #pragma unroll
    for (int j=0;j<8;j++){
      const int d = d0 + j;
      float v = 0.f;
      #pragma unroll
      for (int qq=0; qq<8; ++qq)
        v += scr[((size_t)qq*64 + n_g)*64 + d];
      v /= sdiv;
      size_t idx = (size_t)(n0 + n_g)*64 + d;
      if (fin) v = 0.8f*hp[idx] - 0.1f*cp[idx] + 0.1f*v;
      op[idx] = v;
    }
  }
}

// ---------------------------------------------------------------------------
extern "C" void kernel_launch(void* const* d_in, const int* in_sizes, int n_in,
                              void* d_out, int out_size, void* d_ws, size_t ws_size,
                              hipStream_t stream) {
  const float* x     = (const float*)d_in[0];
  const float* state = (const float*)d_in[1];
  const float* E     = (const float*)d_in[2];
  const float* Wc    = (const float*)d_in[3];
  const float* Wd    = (const float*)d_in[4];
  const float* gw    = (const float*)d_in[5];
  const float* gb    = (const float*)d_in[6];
  const float* uw    = (const float*)d_in[7];
  const float* ub    = (const float*)d_in[8];

  // workspace layout (bytes). Total 73,662,464 B = 70.2 MB.
  char* base = (char*)d_ws;
  u16*   P    = (u16*)(base + 0);           //  8,388,608  (dead after 2nd k_conv)
  u32*   mp2  = (u32*)(base + 0);           //    524,288  (aliases P; written after P dead)
  u32*   mn2  = (u32*)(base + 524288);      //    524,288  (aliases P)
  u8*    msk  = (u8*) (base + 8388608);     //  4,194,304
  u8*    Wc8  = (u8*) (base + 12582912);    //  4,194,304
  u8*    Wd8  = (u8*) (base + 16777216);    //  4,194,304
  u16*   hb16 = (u16*)(base + 20971520);    //  4,194,304
  u8*    ht8p = (u8*) (base + 25165824);    //  2,097,152
  u16*   hfm  = (u16*)(base + 27262976);    //  4,194,304
  float* c1x  = (float*)(base + 31457280);  //    262,144
  float* c1s  = (float*)(base + 31719424);  //  8,388,608
  float* zs   = (float*)(base + 40108032);  //  8,388,608
  float* rws  = (float*)(base + 48496640);  //  8,388,608
  float* c2s  = (float*)(base + 56885248);  //  8,388,608
  float* h    = (float*)(base + 65273856);  //  8,388,608
  float* oc   = c1s;                        // dead after k_gate

  k_w8<<<dim3(32,32,2), 256, 0, stream>>>(Wc, Wd, Wc8, Wd8);
  k_P<<<2048, 256, 0, stream>>>(E, P, msk);
  k_conv<<<dim3(32,16), 256, 0, stream>>>(P, state, c1s, x, c1x, 1);   // + c1x fused

  hipFuncSetAttribute((const void*)k_gate, hipFuncAttributeMaxDynamicSharedMemorySize, GATE_LDS);
  hipFuncSetAttribute((const void*)k_upd,  hipFuncAttributeMaxDynamicSharedMemorySize, GATE_LDS);
  k_gate<<<1024, 512, GATE_LDS, stream>>>(E, gw, gb, x, state, c1x, c1s, zs, rws);
  k_conv<<<dim3(32,16), 256, 0, stream>>>(P, zs, c2s, x, c1x, 0);
  k_upd<<<1024, 512, GATE_LDS, stream>>>(E, uw, ub, x, state, zs, c1x, c2s, rws, h);
  k_hcvt<<<dim3(32,16), 256, 0, stream>>>(h, hb16, ht8p, hfm);
  k_mbits<<<dim3(32,8), 256, 0, stream>>>(msk, mp2, mn2);   // P dead by now

  const int deg_lds = 64*SROW8;   // 131,584 B dynamic (+~4.3 KB static)
  hipFuncSetAttribute((const void*)k_deg, hipFuncAttributeMaxDynamicSharedMemorySize, deg_lds);
  // dispatch 1: connect mask — only Wc8 hot in every XCD L2
  k_deg<<<512, 512, deg_lds, stream>>>(mp2, hb16, Wc8, ht8p, hfm, h, h, oc, 0);
  // dispatch 2: disconnect mask — only Wd8 hot; fused final epilogue -> d_out
  k_deg<<<512, 512, deg_lds, stream>>>(mn2, hb16, Wd8, ht8p, hfm, h, oc, (float*)d_out, 1);
}

// Round 11
// 1004.306 us; speedup vs baseline: 1.0028x; 1.0028x over previous
//
#include <hip/hip_runtime.h>
#include <hip/hip_bf16.h>

typedef unsigned short u16;
typedef unsigned int   u32;
typedef unsigned char  u8;

typedef __attribute__((ext_vector_type(8))) short bf16x8;
typedef __attribute__((ext_vector_type(4))) float f32x4;
typedef __attribute__((ext_vector_type(16))) float f32x16;

static __device__ __forceinline__ float bf2f(u16 u){ return __uint_as_float(((u32)u)<<16); }
static __device__ __forceinline__ u16 f2bf(float f){
  u32 u = __float_as_uint(f);
  u32 r = (u + 0x7fff + ((u>>16)&1)) >> 16;   // RNE; inputs finite
  return (u16)r;
}

// fp8 e4m3 (OCP) helpers — HW cvt, saturating via pre-clamp
static __device__ __forceinline__ u8 f2fp8(float v){
  v = fminf(440.f, fmaxf(-440.f, v));
  return (u8)(__builtin_amdgcn_cvt_pk_fp8_f32(v, 0.f, 0, false) & 0xff);
}
static __device__ __forceinline__ u32 pk4_fp8(float a, float b, float c, float d){
  int w = __builtin_amdgcn_cvt_pk_fp8_f32(a, b, 0, false);
  w = __builtin_amdgcn_cvt_pk_fp8_f32(c, d, w, true);
  return (u32)w;
}

static __device__ __forceinline__ f32x4 mfma_bf16(bf16x8 a, bf16x8 b, f32x4 c){
  return __builtin_amdgcn_mfma_f32_16x16x32_bf16(a, b, c, 0, 0, 0);
}
static __device__ __forceinline__ f32x16 mfma_bf16_32(bf16x8 a, bf16x8 b, f32x16 c){
  return __builtin_amdgcn_mfma_f32_32x32x16_bf16(a, b, c, 0, 0, 0);
}
static __device__ __forceinline__ f32x16 mfma_fp8_32(long a, long b, f32x16 c){
  return __builtin_amdgcn_mfma_f32_32x32x16_fp8_fp8(a, b, c, 0, 0, 0);
}
static __device__ __forceinline__ long lo64(uint4 v){ return (long)(((unsigned long long)v.y<<32) | v.x); }
static __device__ __forceinline__ long hi64(uint4 v){ return (long)(((unsigned long long)v.w<<32) | v.z); }
static __device__ __forceinline__ long mklong(u32 lo, u32 hi){ return (long)(((unsigned long long)hi<<32) | lo); }

// ---------------------------------------------------------------------------
// K-w8: W f32 [m][k] -> fp8 packed, 1KB block per (pt=m/64, kt=k/32, mcp):
//   byte at lane*16 + sel*8 + j = W[pt*64 + (mcp*2+sel)*16 + (lane>>5)*8 + j][kt*32 + (lane&31)]
// grid (32,32,2), block 256.
// ---------------------------------------------------------------------------
__global__ void k_w8(const float* __restrict__ Wc, const float* __restrict__ Wd,
                     u8* __restrict__ Wc8, u8* __restrict__ Wd8){
  __shared__ float tile[64][65];
  const float* src = blockIdx.z ? Wd : Wc;
  u8* dst = blockIdx.z ? Wd8 : Wc8;
  const int m0 = blockIdx.x*64, k0 = blockIdx.y*64;
  const int t = threadIdx.x, r = t & 63, cc = t >> 6;
  #pragma unroll
  for (int j=0;j<4;j++){
    float4 v = *(const float4*)&src[(size_t)(m0+r)*2048 + k0 + cc*16 + j*4];
    tile[r][cc*16+j*4+0]=v.x; tile[r][cc*16+j*4+1]=v.y;
    tile[r][cc*16+j*4+2]=v.z; tile[r][cc*16+j*4+3]=v.w;
  }
  __syncthreads();
  const int lane = t & 63, sub = t >> 6;     // sub 0..3
  const int kth = sub & 1, mcp = sub >> 1;
  const int kl = kth*32 + (lane & 31);       // k within 64-tile
  const int ml = mcp*32 + (lane >> 5)*8;     // m base within 64-tile
  u32 b0 = pk4_fp8(16.f*tile[ml+ 0][kl], 16.f*tile[ml+ 1][kl], 16.f*tile[ml+ 2][kl], 16.f*tile[ml+ 3][kl]);
  u32 b1 = pk4_fp8(16.f*tile[ml+ 4][kl], 16.f*tile[ml+ 5][kl], 16.f*tile[ml+ 6][kl], 16.f*tile[ml+ 7][kl]);
  u32 b2 = pk4_fp8(16.f*tile[ml+16][kl], 16.f*tile[ml+17][kl], 16.f*tile[ml+18][kl], 16.f*tile[ml+19][kl]);
  u32 b3 = pk4_fp8(16.f*tile[ml+20][kl], 16.f*tile[ml+21][kl], 16.f*tile[ml+22][kl], 16.f*tile[ml+23][kl]);
  const int pt = m0 >> 6, kt = (k0 >> 5) + kth;
  u8* dbase = dst + (size_t)((pt*64 + kt)*2 + mcp)*1024 + lane*16;
  *(uint4*)dbase = make_uint4(b0, b1, b2, b3);
}

// ---------------------------------------------------------------------------
// K-hcvt: h f32 [b][m][64] -> hb16 (bf16 row-major), hfm (bf16 frag-major B for
// phase 1), ht8p (fp8 32x32x16-B frags). grid (32,16), block 256.
// ---------------------------------------------------------------------------
__global__ void k_hcvt(const float* __restrict__ h, u16* __restrict__ hb16,
                       u8* __restrict__ ht8p, u16* __restrict__ hfm){
  __shared__ float tile[64][65];
  const int k0 = blockIdx.x*64, b = blockIdx.y;
  const int t = threadIdx.x, r = t & 63, cc = t >> 6;
  const float* src = h + ((size_t)b*2048 + k0)*64;
  u32 hw[8];
  #pragma unroll
  for (int j=0;j<4;j++){
    float4 v = *(const float4*)&src[(size_t)r*64 + cc*16 + j*4];
    tile[r][cc*16+j*4+0]=v.x; tile[r][cc*16+j*4+1]=v.y;
    tile[r][cc*16+j*4+2]=v.z; tile[r][cc*16+j*4+3]=v.w;
    hw[2*j]   = (u32)f2bf(v.x) | ((u32)f2bf(v.y)<<16);
    hw[2*j+1] = (u32)f2bf(v.z) | ((u32)f2bf(v.w)<<16);
  }
  u16* hp = hb16 + (((size_t)b*2048 + k0 + r)*64 + cc*16);
  *(uint4*)hp     = make_uint4(hw[0],hw[1],hw[2],hw[3]);
  *(uint4*)(hp+8) = make_uint4(hw[4],hw[5],hw[6],hw[7]);
  __syncthreads();
  {
    const int lane = t & 63, sub = cc;          // sub = local k16 index 0..3
    const int k16 = (k0 >> 4) + sub;
    const int lr = sub*16 + ((lane >> 5) << 3); // local row in tile
    const int d0 = lane & 31;
    #pragma unroll
    for (int dt=0; dt<2; ++dt){
      const int d = dt*32 + d0;
      u32 w0 = pk4_fp8(tile[lr+0][d], tile[lr+1][d], tile[lr+2][d], tile[lr+3][d]);
      u32 w1 = pk4_fp8(tile[lr+4][d], tile[lr+5][d], tile[lr+6][d], tile[lr+7][d]);
      *(uint2*)(ht8p + (size_t)b*131072 + (size_t)(k16*2 + dt)*512 + lane*8) = make_uint2(w0, w1);
    }
  }
  {
    const int col = k0 + r, ks = cc >> 1, q0 = (cc & 1)*2;
    const int ctg = col >> 4, lcv = col & 15;
    u16* fbase = hfm + (size_t)b*131072 + (size_t)ks*65536 + ((size_t)ctg*64)*8;
    #pragma unroll
    for (int qq=0; qq<2; ++qq){
      int q = q0 + qq;
      u32 p0 = (u32)f2bf(tile[r][ks*32+q*8+0]) | ((u32)f2bf(tile[r][ks*32+q*8+1])<<16);
      u32 p1 = (u32)f2bf(tile[r][ks*32+q*8+2]) | ((u32)f2bf(tile[r][ks*32+q*8+3])<<16);
      u32 p2 = (u32)f2bf(tile[r][ks*32+q*8+4]) | ((u32)f2bf(tile[r][ks*32+q*8+5])<<16);
      u32 p3 = (u32)f2bf(tile[r][ks*32+q*8+6]) | ((u32)f2bf(tile[r][ks*32+q*8+7])<<16);
      *(uint4*)(fbase + (size_t)(q*16 + lcv)*8) = make_uint4(p0,p1,p2,p3);
    }
  }
}

// ---------------------------------------------------------------------------
// K1: row n of A = E E^T. sign-mask (1 pos, 2 neg) + P=softmax(relu) bf16.
// float4 E loads.
// ---------------------------------------------------------------------------
__global__ void k_P(const float* __restrict__ E, u16* __restrict__ P, u8* __restrict__ msk){
  __shared__ float Ew[16];
  __shared__ float arow[2048];
  __shared__ float red[4];
  const int t = threadIdx.x, n = blockIdx.x;
  if (t < 16) Ew[t] = E[n*16 + t];
  __syncthreads();
  float lmax = 0.f;
  for (int i=0;i<8;i++){
    int m = t + 256*i;
    const float4* ep = (const float4*)(E + m*16);
    float4 e0 = ep[0], e1 = ep[1], e2 = ep[2], e3 = ep[3];
    float dot = e0.x*Ew[0] + e0.y*Ew[1] + e0.z*Ew[2] + e0.w*Ew[3]
              + e1.x*Ew[4] + e1.y*Ew[5] + e1.z*Ew[6] + e1.w*Ew[7]
              + e2.x*Ew[8] + e2.y*Ew[9] + e2.z*Ew[10] + e2.w*Ew[11]
              + e3.x*Ew[12] + e3.y*Ew[13] + e3.z*Ew[14] + e3.w*Ew[15];
    msk[n*2048 + m] = dot > 0.f ? (u8)1 : (dot < 0.f ? (u8)2 : (u8)0);
    float ar = fmaxf(dot, 0.f);
    arow[m] = ar;
    lmax = fmaxf(lmax, ar);
  }
  for (int o=1;o<64;o<<=1) lmax = fmaxf(lmax, __shfl_xor(lmax, o));
  if ((t&63)==0) red[t>>6] = lmax;
  __syncthreads();
  float gmax = fmaxf(fmaxf(red[0],red[1]), fmaxf(red[2],red[3]));
  __syncthreads();
  float lsum = 0.f;
  for (int i=0;i<8;i++){
    int m = t + 256*i;
    float e = expf(arow[m] - gmax);
    arow[m] = e;
    lsum += e;
  }
  for (int o=1;o<64;o<<=1) lsum += __shfl_xor(lsum, o);
  if ((t&63)==0) red[t>>6] = lsum;
  __syncthreads();
  float inv = 1.f/(red[0]+red[1]+red[2]+red[3]);
  for (int i=0;i<8;i++){
    int m = t + 256*i;
    P[n*2048 + m] = f2bf(arow[m]*inv);
  }
}

// ---------------------------------------------------------------------------
// K-mbits: LDS-tiled transpose bitmap build. grid (32, 8), block 256.
// ---------------------------------------------------------------------------
__global__ void k_mbits(const u8* __restrict__ msk, u32* __restrict__ mp2, u32* __restrict__ mn2){
  __shared__ u8 tile[256][72];
  const int m0 = blockIdx.x*64, n0 = blockIdx.y*256;
  const int t = threadIdx.x;
  {
    const u8* src = msk + (size_t)(n0 + t)*2048 + m0;
    #pragma unroll
    for (int j=0;j<8;j++)
      *(uint2*)&tile[t][j*8] = *(const uint2*)(src + j*8);
  }
  __syncthreads();
  const int m = t & 63, g = t >> 6;
  #pragma unroll
  for (int jj=0; jj<2; ++jj){
    const int j = g + jj*4;                 // n-word 0..7 within tile
    u32 bp = 0, bn = 0;
    #pragma unroll
    for (int i=0;i<32;++i){
      u8 v = tile[j*32 + i][m];
      bp |= (u32)(v == (u8)1) << i;
      bn |= (u32)(v == (u8)2) << i;
    }
    const size_t wi = (size_t)((n0 >> 5) + j)*2048 + m0 + m;
    mp2[wi] = bp;
    mn2[wi] = bn;
  }
}

// ---------------------------------------------------------------------------
// K2: Y[b,n,d] = sum_m P[n,m] * Z[b,m,d] via bf16 MFMA with hi/lo split.
// withx=1 additionally computes c1x from the staged P tile.
// grid (32,16), block 256.
// ---------------------------------------------------------------------------
__global__ void k_conv(const u16* __restrict__ P, const float* __restrict__ Z, float* __restrict__ Y,
                       const float* __restrict__ x, float* __restrict__ c1x, int withx){
  __shared__ u16 Pt[64][68];
  __shared__ u16 Zhi[64][68];
  __shared__ u16 Zlo[64][68];
  __shared__ float xt[64][2];
  const int t = threadIdx.x;
  const int w = t >> 6, lane = t & 63, l32 = lane & 31, h32 = lane >> 5;
  const int nh = w & 1, dh = w >> 1;
  const int n0 = blockIdx.x*64, b = blockIdx.y;
  const int mloc = t & 63, grp = t >> 6;
  f32x16 acch = (f32x16)(0.f), accl = (f32x16)(0.f);
  float xacc = 0.f;
  const int xnl = t >> 2, xc = (t >> 1) & 1, xmh = t & 1;
  for (int mc = 0; mc < 32; ++mc){
    const int m0 = mc*64;
    {
      const u16* pp = P + (size_t)(n0 + mloc)*2048 + m0 + grp*16;
      uint4 v0 = *(const uint4*)pp;
      uint4 v1 = *(const uint4*)(pp + 8);
      *(uint4*)&Pt[mloc][grp*16]     = v0;
      *(uint4*)&Pt[mloc][grp*16 + 8] = v1;
      const float* zp = Z + ((size_t)b*2048 + m0 + mloc)*64 + grp*16;
      #pragma unroll
      for (int jj = 0; jj < 4; ++jj){
        float4 zv = *(const float4*)(zp + jj*4);
        const int dd = grp*16 + jj*4;
        u16 h0 = f2bf(zv.x); Zhi[dd+0][mloc] = h0; Zlo[dd+0][mloc] = f2bf(zv.x - bf2f(h0));
        u16 h1 = f2bf(zv.y); Zhi[dd+1][mloc] = h1; Zlo[dd+1][mloc] = f2bf(zv.y - bf2f(h1));
        u16 h2 = f2bf(zv.z); Zhi[dd+2][mloc] = h2; Zlo[dd+2][mloc] = f2bf(zv.z - bf2f(h2));
        u16 h3 = f2bf(zv.w); Zhi[dd+3][mloc] = h3; Zlo[dd+3][mloc] = f2bf(zv.w - bf2f(h3));
      }
      if (withx && t < 128)
        xt[t>>1][t&1] = x[((size_t)b*2048 + m0 + (t>>1))*2 + (t&1)];
    }
    __syncthreads();
    #pragma unroll
    for (int kt = 0; kt < 4; ++kt){
      bf16x8 a  = *(const bf16x8*)&Pt[nh*32 + l32][kt*16 + h32*8];
      bf16x8 bh = *(const bf16x8*)&Zhi[dh*32 + l32][kt*16 + h32*8];
      bf16x8 bl = *(const bf16x8*)&Zlo[dh*32 + l32][kt*16 + h32*8];
      acch = mfma_bf16_32(a, bh, acch);
      accl = mfma_bf16_32(a, bl, accl);
    }
    if (withx){
      #pragma unroll
      for (int mi = 0; mi < 32; ++mi){
        const int ml = xmh*32 + mi;
        xacc += bf2f(Pt[xnl][ml])*xt[ml][xc];
      }
    }
    __syncthreads();
  }
  #pragma unroll
  for (int g = 0; g < 16; ++g){
    const int row = (g&3) + 8*(g>>2) + 4*h32;
    Y[((size_t)b*2048 + n0 + nh*32 + row)*64 + dh*32 + l32] = acch[g] + accl[g];
  }
  if (withx){
    float o = xacc + __shfl_xor(xacc, 1);
    if (xmh == 0)
      c1x[((size_t)b*2048 + n0 + xnl)*2 + xc] = o;
  }
}

// ---------------------------------------------------------------------------
// K3: gate SAGC -> zs = z*state, rws = r. One block per node n.
// (R18: reverted to 1-node form — R17's 2-node/halved-gw-stream variant
// measured neutral: gate/upd are latency/barrier-bound, not L2-BW-bound.)
// ---------------------------------------------------------------------------
__global__ void k_gate(const float* __restrict__ E, const float* __restrict__ gw, const float* __restrict__ gb,
                       const float* __restrict__ x, const float* __restrict__ state,
                       const float* __restrict__ c1x, const float* __restrict__ c1s,
                       float* __restrict__ zs, float* __restrict__ rws){
  __shared__ float Ew[16];
  __shared__ float bnv[128];
  __shared__ float Wn[2][66][64];
  __shared__ float xg4[4][2][66];
  const int t = threadIdx.x, n = blockIdx.x;
  if (t < 16) Ew[t] = E[n*16 + t];
  __syncthreads();
  if (t < 128){
    float a = 0.f;
    #pragma unroll
    for (int e=0;e<16;e++) a += Ew[e]*gb[e*128 + t];
    bnv[t] = a;
  }
  for (int half=0; half<2; ++half){
    for (int idx=t; idx<8448; idx+=256){
      int o = idx & 63, rest = idx>>6, i = rest % 66, k = rest / 66;
      float a = 0.f;
      #pragma unroll
      for (int e=0;e<16;e++) a += Ew[e]*gw[((e*2+k)*66 + i)*128 + half*64 + o];
      Wn[k][i][o] = a;
    }
    __syncthreads();
    for (int bb=0; bb<4; ++bb){
      for (int idx=t; idx<528; idx+=256){
        int bi = idx/132, rem = idx%132, k = rem/66, i = rem%66;
        int b = bb*4 + bi;
        float v;
        if (k==0) v = (i<2) ? x[((size_t)b*2048+n)*2 + i] : state[((size_t)b*2048+n)*64 + (i-2)];
        else      v = (i<2) ? c1x[((size_t)b*2048+n)*2 + i] : c1s[((size_t)b*2048+n)*64 + (i-2)];
        xg4[bi][k][i] = v;
      }
      __syncthreads();
      {
        int bi = t>>6, o = t&63, b = bb*4 + bi;
        float a = 0.f;
        #pragma unroll
        for (int k=0;k<2;k++)
          for (int i=0;i<66;i++) a += xg4[bi][k][i]*Wn[k][i][o];
        a += bnv[half*64 + o];
        float s = 1.f/(1.f + expf(-a));
        if (half==0) zs[((size_t)b*2048+n)*64 + o] = s*state[((size_t)b*2048+n)*64 + o];
        else         rws[((size_t)b*2048+n)*64 + o] = s;
      }
      __syncthreads();
    }
  }
}

// ---------------------------------------------------------------------------
// K3b: update SAGC -> hc -> h = r*state + (1-r)*hc. (1-node form, see k_gate.)
// ---------------------------------------------------------------------------
__global__ void k_upd(const float* __restrict__ E, const float* __restrict__ uw, const float* __restrict__ ub,
                      const float* __restrict__ x, const float* __restrict__ state,
                      const float* __restrict__ zs, const float* __restrict__ c1x, const float* __restrict__ c2s,
                      const float* __restrict__ rws, float* __restrict__ h){
  __shared__ float Ew[16];
  __shared__ float bnu[64];
  __shared__ float Wn[2][66][64];
  __shared__ float xg4[4][2][66];
  const int t = threadIdx.x, n = blockIdx.x;
  if (t < 16) Ew[t] = E[n*16 + t];
  __syncthreads();
  if (t < 64){
    float a = 0.f;
    #pragma unroll
    for (int e=0;e<16;e++) a += Ew[e]*ub[e*64 + t];
    bnu[t] = a;
  }
  for (int idx=t; idx<8448; idx+=256){
    int o = idx & 63, rest = idx>>6, i = rest % 66, k = rest / 66;
    float a = 0.f;
    #pragma unroll
    for (int e=0;e<16;e++) a += Ew[e]*uw[((e*2+k)*66 + i)*64 + o];
    Wn[k][i][o] = a;
  }
  __syncthreads();
  for (int bb=0; bb<4; ++bb){
    for (int idx=t; idx<528; idx+=256){
      int bi = idx/132, rem = idx%132, k = rem/66, i = rem%66;
      int b = bb*4 + bi;
      float v;
      if (k==0) v = (i<2) ? x[((size_t)b*2048+n)*2 + i] : zs[((size_t)b*2048+n)*64 + (i-2)];
      else      v = (i<2) ? c1x[((size_t)b*2048+n)*2 + i] : c2s[((size_t)b*2048+n)*64 + (i-2)];
      xg4[bi][k][i] = v;
    }
    __syncthreads();
    {
      int bi = t>>6, o = t&63, b = bb*4 + bi;
      float a = 0.f;
      #pragma unroll
      for (int k=0;k<2;k++)
        for (int i=0;i<66;i++) a += xg4[bi][k][i]*Wn[k][i][o];
      float hc = tanhf(a + bnu[o]);
      float rv = rws[((size_t)b*2048+n)*64 + o];
      h[((size_t)b*2048+n)*64 + o] = rv*state[((size_t)b*2048+n)*64 + o] + (1.f - rv)*hc;
    }
    __syncthreads();
  }
}

// ---------------------------------------------------------------------------
// sm_step2: both n-halves' online-softmax steps fused; ht frags loaded once.
// ---------------------------------------------------------------------------
static __device__ __forceinline__ void sm_step2(
    f32x16& L00, f32x16& L10, f32x16& L01, f32x16& L11,
    f32x16& oA0, f32x16& oA1, f32x16& oB0, f32x16& oB1,
    float& mrun0, float& srun0, float& mrun1, float& srun1,
    const u8* __restrict__ htb, int ktA, int ktB, int lane, int h32){
  const float LN256 = 5.545177444479562f;
  float c0 = L00[0], c1 = L01[0];
  #pragma unroll
  for (int g=1; g<16; ++g){ c0 = fmaxf(c0, L00[g]); c1 = fmaxf(c1, L01[g]); }
  #pragma unroll
  for (int g=0; g<16; ++g){ c0 = fmaxf(c0, L10[g]); c1 = fmaxf(c1, L11[g]); }
  c0 = fmaxf(c0, __shfl_xor(c0, 32));
  c1 = fmaxf(c1, __shfl_xor(c1, 32));
  float mnew0 = fmaxf(mrun0, 0.5f*c0);
  float mnew1 = fmaxf(mrun1, 0.5f*c1);
  float sc0 = __expf(mrun0 - mnew0);
  float sc1 = __expf(mrun1 - mnew1);
  srun0 *= sc0; srun1 *= sc1;
  #pragma unroll
  for (int g=0; g<16; ++g){
    const int rowl = (g&3) + 8*(g>>2) + 4*h32;
    float f0 = __shfl(sc0, rowl);
    float f1 = __shfl(sc1, rowl);
    oA0[g] *= f0; oA1[g] *= f0;
    oB0[g] *= f1; oB1[g] *= f1;
  }
  float cs0 = 0.f, cs1 = 0.f;
  #pragma unroll
  for (int kti=0; kti<2; ++kti){
    const int kt = kti ? ktB : ktA;
    long h00 = *(const long*)(htb + (size_t)((kt*2+0)*2 + 0)*512 + lane*8);
    long h01 = *(const long*)(htb + (size_t)((kt*2+0)*2 + 1)*512 + lane*8);
    long h10 = *(const long*)(htb + (size_t)((kt*2+1)*2 + 0)*512 + lane*8);
    long h11 = *(const long*)(htb + (size_t)((kt*2+1)*2 + 1)*512 + lane*8);
    float p0[16], p1[16];
    #pragma unroll
    for (int g=0; g<16; ++g){
      float La = kti ? L10[g] : L00[g];
      float Lb = kti ? L11[g] : L01[g];
      p0[g] = __expf(0.5f*La - mnew0 + LN256);   // 256-scaled
      p1[g] = __expf(0.5f*Lb - mnew1 + LN256);
      cs0 += p0[g]; cs1 += p1[g];
    }
    u32 qA0 = pk4_fp8(p0[0],p0[1],p0[2],p0[3]);
    u32 qB0 = pk4_fp8(p0[4],p0[5],p0[6],p0[7]);
    u32 qC0 = pk4_fp8(p0[8],p0[9],p0[10],p0[11]);
    u32 qD0 = pk4_fp8(p0[12],p0[13],p0[14],p0[15]);
    u32 qA1 = pk4_fp8(p1[0],p1[1],p1[2],p1[3]);
    u32 qB1 = pk4_fp8(p1[4],p1[5],p1[6],p1[7]);
    u32 qC1 = pk4_fp8(p1[8],p1[9],p1[10],p1[11]);
    u32 qD1 = pk4_fp8(p1[12],p1[13],p1[14],p1[15]);
    u32 xA0 = __shfl_xor(qA0,32), xB0 = __shfl_xor(qB0,32);
    u32 xC0 = __shfl_xor(qC0,32), xD0 = __shfl_xor(qD0,32);
    u32 xA1 = __shfl_xor(qA1,32), xB1 = __shfl_xor(qB1,32);
    u32 xC1 = __shfl_xor(qC1,32), xD1 = __shfl_xor(qD1,32);
    long pf00 = h32 ? mklong(xB0,qB0) : mklong(qA0,xA0);
    long pf01 = h32 ? mklong(xD0,qD0) : mklong(qC0,xC0);
    long pf10 = h32 ? mklong(xB1,qB1) : mklong(qA1,xA1);
    long pf11 = h32 ? mklong(xD1,qD1) : mklong(qC1,xC1);
    oA0 = mfma_fp8_32(pf00, h00, oA0);
    oA1 = mfma_fp8_32(pf00, h01, oA1);
    oB0 = mfma_fp8_32(pf10, h00, oB0);
    oB1 = mfma_fp8_32(pf10, h01, oB1);
    oA0 = mfma_fp8_32(pf01, h10, oA0);
    oA1 = mfma_fp8_32(pf01, h11, oA1);
    oB0 = mfma_fp8_32(pf11, h10, oB0);
    oB1 = mfma_fp8_32(pf11, h11, oB1);
  }
  cs0 += __shfl_xor(cs0, 32);
  cs1 += __shfl_xor(cs1, 32);
  srun0 += cs0; srun1 += cs1;
  mrun0 = mnew0; mrun1 = mnew1;
}

// ---------------------------------------------------------------------------
// K5: fused degrees — R18 (= R15 best-known): wave = 64 n-rows x 256 k-cols,
// W tiled once per block, flash online-softmax, sm_step2, W double-buffer,
// setprio. (R17's anti-phase si stagger REVERTED: measured −2% MfmaUtil —
// waves were not harmfully lockstepped; stagger hurt W L1 temporal locality.)
// ---------------------------------------------------------------------------
#define SROW8 2056

__global__ void __launch_bounds__(512,2) k_deg(
    const u32* __restrict__ mbits, const u16* __restrict__ hb16,
    const u8* __restrict__ W8,
    const u8* __restrict__ ht8p, const u16* __restrict__ hfm,
    const float* __restrict__ hf32, const float* __restrict__ oc_in,
    float* __restrict__ outp, int fin){
  extern __shared__ u8 S[];
  __shared__ float maxw[64][8];
  __shared__ float sumw[64][8];
  __shared__ float sgl_lds[64];
  const int t = threadIdx.x;
  const int w = t >> 6, lane = t & 63, lc = lane & 15, q = lane >> 4;
  const int l32 = lane & 31, h32 = lane >> 5;
  const int id = blockIdx.x;
  const int b = id >> 5, n0 = (id & 31) * 64;
  const int p0 = (id >> 3) & 31;          // per-CU-within-XCD rotation offset
  const u32* mrow0 = mbits + (size_t)(n0 >> 5)*2048;
  const u32* mrow1 = mrow0 + 2048;
  const u16* hbb = hb16 + (size_t)b*2048*64;
  const u16* hfb = hfm + (size_t)b*131072;
  const u8* htb = ht8p + (size_t)b*131072;

  // ---- phase 1: S[r][m] = fp8( (bit ? h_n.h_m : 0) / 8 ), 64 rows ----
  {
    const int c0 = p0 & 15;
    bf16x8 A[4][2];
    #pragma unroll
    for (int rt=0; rt<4; ++rt)
      #pragma unroll
      for (int ks=0; ks<2; ++ks)
        A[rt][ks] = *(const bf16x8*)&hbb[(size_t)(n0 + rt*16 + lc)*64 + ks*32 + q*8];
    int ctg0 = w*16 + c0;
    bf16x8 B0c = *(const bf16x8*)(hfb + (size_t)ctg0*512 + lane*8);
    bf16x8 B1c = *(const bf16x8*)(hfb + 65536 + (size_t)ctg0*512 + lane*8);
    u32 m0c = mrow0[ctg0*16 + lc], m1c = mrow1[ctg0*16 + lc];
    #pragma unroll 1
    for (int ct=0; ct<16; ++ct){
      const int ctg  = w*16 + ((ct + c0) & 15);
      const int ctgn = w*16 + ((ct + 1 + c0) & 15);
      bf16x8 B0n = *(const bf16x8*)(hfb + (size_t)ctgn*512 + lane*8);
      bf16x8 B1n = *(const bf16x8*)(hfb + 65536 + (size_t)ctgn*512 + lane*8);
      u32 m0n = mrow0[ctgn*16 + lc], m1n = mrow1[ctgn*16 + lc];
      const int mcol = ctg*16 + lc;
      f32x4 a[4];
      #pragma unroll
      for (int rt=0; rt<4; ++rt){
        a[rt] = (f32x4){0.f,0.f,0.f,0.f};
        a[rt] = mfma_bf16(A[rt][0], B0c, a[rt]);
        a[rt] = mfma_bf16(A[rt][1], B1c, a[rt]);
      }
      #pragma unroll
      for (int rt=0; rt<4; ++rt){
        const u32 mw = (rt < 2) ? m0c : m1c;
        #pragma unroll
        for (int i=0;i<4;i++){
          const int row = rt*16 + q*4 + i;
          float v = ((mw >> (row & 31)) & 1u) ? a[rt][i]*0.125f : 0.f;
          S[row*SROW8 + mcol] = f2fp8(v);
        }
      }
      B0c = B0n; B1c = B1n; m0c = m0n; m1c = m1n;
    }
  }
  __syncthreads();

  // ---- fused phases 2+3+4: wave w owns k-cols [w*256,(w+1)*256), all 64 n ----
  const u8* sb0 = S + (size_t)l32*SROW8 + h32*8;          // nh0 rows
  const u8* sb1 = S + (size_t)(32 + l32)*SROW8 + h32*8;   // nh1 rows
  const u8* wl = W8 + lane*16;
  f32x16 oA0 = (f32x16)(0.f), oA1 = (f32x16)(0.f);        // nh0: dt0, dt1
  f32x16 oB0 = (f32x16)(0.f), oB1 = (f32x16)(0.f);        // nh1
  float mrun0 = -1e30f, srun0 = 0.f, mrun1 = -1e30f, srun1 = 0.f;
  #pragma unroll 1
  for (int si = 0; si < 4; ++si){
    const int ktA = w*8 + si*2, ktB = ktA + 1;
    f32x16 L00 = (f32x16)(0.f), L01 = (f32x16)(0.f);      // kti0: nh0, nh1
    f32x16 L10 = (f32x16)(0.f), L11 = (f32x16)(0.f);      // kti1
    uint4 wv0, wv1, wv2, wv3;
    {
      const int pt0 = p0;
      wv0 = *(const uint4*)(wl + (size_t)((pt0*64 + ktA)*2 + 0)*1024);
      wv1 = *(const uint4*)(wl + (size_t)((pt0*64 + ktA)*2 + 1)*1024);
      wv2 = *(const uint4*)(wl + (size_t)((pt0*64 + ktB)*2 + 0)*1024);
      wv3 = *(const uint4*)(wl + (size_t)((pt0*64 + ktB)*2 + 1)*1024);
    }
    __builtin_amdgcn_s_setprio(1);
    #pragma unroll 1
    for (int pti = 0; pti < 32; ++pti){
      const int pt  = (pti + p0) & 31;
      const int ptn = (pti + 1 + p0) & 31;
      long b00 = *(const long*)(sb0 + pt*64 +  0);
      long b01 = *(const long*)(sb0 + pt*64 + 16);
      long b02 = *(const long*)(sb0 + pt*64 + 32);
      long b03 = *(const long*)(sb0 + pt*64 + 48);
      long b10 = *(const long*)(sb1 + pt*64 +  0);
      long b11 = *(const long*)(sb1 + pt*64 + 16);
      long b12 = *(const long*)(sb1 + pt*64 + 32);
      long b13 = *(const long*)(sb1 + pt*64 + 48);
      uint4 wn0 = *(const uint4*)(wl + (size_t)((ptn*64 + ktA)*2 + 0)*1024);
      uint4 wn1 = *(const uint4*)(wl + (size_t)((ptn*64 + ktA)*2 + 1)*1024);
      uint4 wn2 = *(const uint4*)(wl + (size_t)((ptn*64 + ktB)*2 + 0)*1024);
      uint4 wn3 = *(const uint4*)(wl + (size_t)((ptn*64 + ktB)*2 + 1)*1024);
      L00 = mfma_fp8_32(lo64(wv0), b00, L00);
      L01 = mfma_fp8_32(lo64(wv0), b10, L01);
      L10 = mfma_fp8_32(lo64(wv2), b00, L10);
      L11 = mfma_fp8_32(lo64(wv2), b10, L11);
      L00 = mfma_fp8_32(hi64(wv0), b01, L00);
      L01 = mfma_fp8_32(hi64(wv0), b11, L01);
      L10 = mfma_fp8_32(hi64(wv2), b01, L10);
      L11 = mfma_fp8_32(hi64(wv2), b11, L11);
      L00 = mfma_fp8_32(lo64(wv1), b02, L00);
      L01 = mfma_fp8_32(lo64(wv1), b12, L01);
      L10 = mfma_fp8_32(lo64(wv3), b02, L10);
      L11 = mfma_fp8_32(lo64(wv3), b12, L11);
      L00 = mfma_fp8_32(hi64(wv1), b03, L00);
      L01 = mfma_fp8_32(hi64(wv1), b13, L01);
      L10 = mfma_fp8_32(hi64(wv3), b03, L10);
      L11 = mfma_fp8_32(hi64(wv3), b13, L11);
      wv0 = wn0; wv1 = wn1; wv2 = wn2; wv3 = wn3;
    }
    __builtin_amdgcn_s_setprio(0);
    sm_step2(L00, L10, L01, L11, oA0, oA1, oB0, oB1,
             mrun0, srun0, mrun1, srun1, htb, ktA, ktB, lane, h32);
  }

  // ---- merge: log-sum-exp combine of 8 k-slices ----
  if (h32 == 0){
    maxw[l32][w] = mrun0;      sumw[l32][w] = srun0;
    maxw[32 + l32][w] = mrun1; sumw[32 + l32][w] = srun1;
  }
  __syncthreads();                        // all S reads done; max/sum visible
  float* scr = (float*)S;
  {
    float m_g0 = maxw[l32][0];
    #pragma unroll
    for (int j=1;j<8;j++) m_g0 = fmaxf(m_g0, maxw[l32][j]);
    float s_g0 = 0.f;
    #pragma unroll
    for (int j=0;j<8;j++) s_g0 += sumw[l32][j]*__expf(maxw[l32][j]-m_g0);
    float m_g1 = maxw[32+l32][0];
    #pragma unroll
    for (int j=1;j<8;j++) m_g1 = fmaxf(m_g1, maxw[32+l32][j]);
    float s_g1 = 0.f;
    #pragma unroll
    for (int j=0;j<8;j++) s_g1 += sumw[32+l32][j]*__expf(maxw[32+l32][j]-m_g1);
    if (w == 0 && h32 == 0){
      sgl_lds[l32] = s_g0;
      sgl_lds[32 + l32] = s_g1;
    }
    float f0 = __expf(mrun0 - m_g0);
    float f1 = __expf(mrun1 - m_g1);
    #pragma unroll
    for (int g=0; g<16; ++g){
      const int rowl = (g&3) + 8*(g>>2) + 4*h32;
      float fr0 = __shfl(f0, rowl);
      float fr1 = __shfl(f1, rowl);
      scr[((size_t)w*64 + rowl)*64 + l32]           = oA0[g]*fr0;
      scr[((size_t)w*64 + rowl)*64 + 32 + l32]      = oA1[g]*fr0;
      scr[((size_t)w*64 + 32 + rowl)*64 + l32]      = oB0[g]*fr1;
      scr[((size_t)w*64 + 32 + rowl)*64 + 32 + l32] = oB1[g]*fr1;
    }
  }
  __syncthreads();

  // ---- reduce 8 partials + epilogue ----
  {
    const int n_g = t >> 3, d0 = (t & 7)*8;
    const float sdiv = sgl_lds[n_g];
    float* op = outp + (size_t)b*2048*64;
    const float* hp = hf32 + (size_t)b*2048*64;
    const float* cp = oc_in + (size_t)b*2048*64;
    #pragma unroll
    for (int j=0;j<8;j++){
      const int d = d0 + j;
      float v = 0.f;
      #pragma unroll
      for (int qq=0; qq<8; ++qq)
        v += scr[((size_t)qq*64 + n_g)*64 + d];
      v /= sdiv;
      size_t idx = (size_t)(n0 + n_g)*64 + d;
      if (fin) v = 0.8f*hp[idx] - 0.1f*cp[idx] + 0.1f*v;
      op[idx] = v;
    }
  }
}

// ---------------------------------------------------------------------------
extern "C" void kernel_launch(void* const* d_in, const int* in_sizes, int n_in,
                              void* d_out, int out_size, void* d_ws, size_t ws_size,
                              hipStream_t stream) {
  const float* x     = (const float*)d_in[0];
  const float* state = (const float*)d_in[1];
  const float* E     = (const float*)d_in[2];
  const float* Wc    = (const float*)d_in[3];
  const float* Wd    = (const float*)d_in[4];
  const float* gw    = (const float*)d_in[5];
  const float* gb    = (const float*)d_in[6];
  const float* uw    = (const float*)d_in[7];
  const float* ub    = (const float*)d_in[8];

  // workspace layout (bytes). Total 73,662,464 B = 70.2 MB.
  char* base = (char*)d_ws;
  u16*   P    = (u16*)(base + 0);           //  8,388,608  (dead after 2nd k_conv)
  u32*   mp2  = (u32*)(base + 0);           //    524,288  (aliases P; written after P dead)
  u32*   mn2  = (u32*)(base + 524288);      //    524,288  (aliases P)
  u8*    msk  = (u8*) (base + 8388608);     //  4,194,304
  u8*    Wc8  = (u8*) (base + 12582912);    //  4,194,304
  u8*    Wd8  = (u8*) (base + 16777216);    //  4,194,304
  u16*   hb16 = (u16*)(base + 20971520);    //  4,194,304
  u8*    ht8p = (u8*) (base + 25165824);    //  2,097,152
  u16*   hfm  = (u16*)(base + 27262976);    //  4,194,304
  float* c1x  = (float*)(base + 31457280);  //    262,144
  float* c1s  = (float*)(base + 31719424);  //  8,388,608
  float* zs   = (float*)(base + 40108032);  //  8,388,608
  float* rws  = (float*)(base + 48496640);  //  8,388,608
  float* c2s  = (float*)(base + 56885248);  //  8,388,608
  float* h    = (float*)(base + 65273856);  //  8,388,608
  float* oc   = c1s;                        // dead after k_gate

  k_w8<<<dim3(32,32,2), 256, 0, stream>>>(Wc, Wd, Wc8, Wd8);
  k_P<<<2048, 256, 0, stream>>>(E, P, msk);
  k_conv<<<dim3(32,16), 256, 0, stream>>>(P, state, c1s, x, c1x, 1);   // + c1x fused
  k_gate<<<2048, 256, 0, stream>>>(E, gw, gb, x, state, c1x, c1s, zs, rws);
  k_conv<<<dim3(32,16), 256, 0, stream>>>(P, zs, c2s, x, c1x, 0);
  k_upd<<<2048, 256, 0, stream>>>(E, uw, ub, x, state, zs, c1x, c2s, rws, h);
  k_hcvt<<<dim3(32,16), 256, 0, stream>>>(h, hb16, ht8p, hfm);
  k_mbits<<<dim3(32,8), 256, 0, stream>>>(msk, mp2, mn2);   // P dead by now

  const int deg_lds = 64*SROW8;   // 131,584 B dynamic (+~4.3 KB static)
  hipFuncSetAttribute((const void*)k_deg, hipFuncAttributeMaxDynamicSharedMemorySize, deg_lds);
  // dispatch 1: connect mask — only Wc8 hot in every XCD L2
  k_deg<<<512, 512, deg_lds, stream>>>(mp2, hb16, Wc8, ht8p, hfm, h, h, oc, 0);
  // dispatch 2: disconnect mask — only Wd8 hot; fused final epilogue -> d_out
  k_deg<<<512, 512, deg_lds, stream>>>(mn2, hb16, Wd8, ht8p, hfm, h, oc, (float*)d_out, 1);
}